// Round 1
// baseline (5995.855 us; speedup 1.0000x reference)
//
#include <hip/hip_runtime.h>
#include <hip/hip_bf16.h>

// Encoder: h = normalize_rows(x @ W1^T + b1) * 1.8 ; APPNP K=10, alpha=0.15
// N=100000, E=3200000, IN=512, OUT=256. Output fp32 [N,256].
//
// Strategy:
//  - fp32 tiled GEMM (no fp32 MFMA on CDNA4; 26 GFLOP -> ~300us on vector ALU)
//  - row normalize
//  - build CSR by dst (incl. self-loops) once per call: count -> scan -> fill
//  - 10x pull-SpMM: one wave per dst row, lane owns 4 cols (float4 gather),
//    agg[d] = dinv[d] * sum_e dinv[src_e] * z[src_e]; z fits L3 (102MB)

#define ALPHA 0.15f
#define BETA 0.85f
#define SCALE 1.8f

// ---------------- transpose W1 [256][512] -> Wt [512][256] ----------------
__global__ void transpose_w(const float* __restrict__ W1, float* __restrict__ Wt) {
    int i = blockIdx.x * blockDim.x + threadIdx.x;   // 512*256
    if (i >= 512 * 256) return;
    int k = i >> 8;          // 0..511
    int n = i & 255;         // 0..255
    Wt[i] = W1[n * 512 + k];
}

// ---------------- fp32 GEMM: C[M,256] = A[M,512] * B[512,256] + bias ------
__global__ __launch_bounds__(256) void gemm_kernel(
    const float* __restrict__ A, const float* __restrict__ B,
    const float* __restrict__ bias, float* __restrict__ C, int M) {
    __shared__ float As[16][65];   // [k][m], padded
    __shared__ float Bs[16][64];   // [k][n]
    const int tid = threadIdx.x;
    const int tx = tid & 15;       // n-dim
    const int ty = tid >> 4;       // m-dim
    const int m0 = blockIdx.x * 64;
    const int n0 = blockIdx.y * 64;

    float acc[4][4];
#pragma unroll
    for (int i = 0; i < 4; i++)
#pragma unroll
        for (int j = 0; j < 4; j++) acc[i][j] = 0.0f;

    const int arow = tid >> 2;          // 0..63
    const int akseg = tid & 3;          // 0..3 (4 k-floats each)
    const int bkk = tid >> 4;           // 0..15
    const int bnseg = tid & 15;         // 0..15

    for (int k0 = 0; k0 < 512; k0 += 16) {
        // A tile 64x16
        float4 av = make_float4(0.f, 0.f, 0.f, 0.f);
        if (m0 + arow < M)
            av = *(const float4*)(A + (size_t)(m0 + arow) * 512 + k0 + akseg * 4);
        As[akseg * 4 + 0][arow] = av.x;
        As[akseg * 4 + 1][arow] = av.y;
        As[akseg * 4 + 2][arow] = av.z;
        As[akseg * 4 + 3][arow] = av.w;
        // B tile 16x64
        float4 bv = *(const float4*)(B + (size_t)(k0 + bkk) * 256 + n0 + bnseg * 4);
        *(float4*)(&Bs[bkk][bnseg * 4]) = bv;
        __syncthreads();

#pragma unroll
        for (int kk = 0; kk < 16; kk++) {
            float a[4], b[4];
#pragma unroll
            for (int i = 0; i < 4; i++) a[i] = As[kk][ty * 4 + i];
#pragma unroll
            for (int j = 0; j < 4; j++) b[j] = Bs[kk][tx * 4 + j];
#pragma unroll
            for (int i = 0; i < 4; i++)
#pragma unroll
                for (int j = 0; j < 4; j++) acc[i][j] += a[i] * b[j];
        }
        __syncthreads();
    }

    float4 bias4 = *(const float4*)(bias + n0 + tx * 4);
#pragma unroll
    for (int i = 0; i < 4; i++) {
        int m = m0 + ty * 4 + i;
        if (m < M) {
            float4 o;
            o.x = acc[i][0] + bias4.x;
            o.y = acc[i][1] + bias4.y;
            o.z = acc[i][2] + bias4.z;
            o.w = acc[i][3] + bias4.w;
            *(float4*)(C + (size_t)m * 256 + n0 + tx * 4) = o;
        }
    }
}

// ---------------- row L2-normalize * 1.8, in place ------------------------
__global__ __launch_bounds__(256) void normalize_kernel(float* __restrict__ h, int N) {
    int n = blockIdx.x;
    if (n >= N) return;
    int t = threadIdx.x;
    float v = h[(size_t)n * 256 + t];
    float ss = v * v;
#pragma unroll
    for (int off = 32; off > 0; off >>= 1) ss += __shfl_down(ss, off, 64);
    __shared__ float wsum[4];
    int w = t >> 6, lane = t & 63;
    if (lane == 0) wsum[w] = ss;
    __syncthreads();
    float tot = wsum[0] + wsum[1] + wsum[2] + wsum[3];
    float nrm = sqrtf(tot);
    float s = SCALE / fmaxf(nrm, 1e-12f);
    h[(size_t)n * 256 + t] = v * s;
}

// ---------------- degree / CSR build --------------------------------------
__global__ void init_counts(int* __restrict__ counts, int N) {
    int i = blockIdx.x * blockDim.x + threadIdx.x;
    if (i < N) counts[i] = 1;   // self-loop
}

__global__ void count_kernel(const int* __restrict__ dst, int* __restrict__ counts, int E) {
    int i = blockIdx.x * blockDim.x + threadIdx.x;
    if (i < E) atomicAdd(&counts[dst[i]], 1);
}

__global__ void dinv_kernel(const int* __restrict__ counts, float* __restrict__ dinv, int N) {
    int i = blockIdx.x * blockDim.x + threadIdx.x;
    if (i < N) dinv[i] = rsqrtf((float)counts[i]);
}

__global__ __launch_bounds__(256) void scan_phase1(
    const int* __restrict__ counts, int* __restrict__ offsets,
    int* __restrict__ blocksums, int N) {
    __shared__ int sdata[256];
    int b = blockIdx.x;
    int base = b * 1024;
    int t = threadIdx.x;
    int v[4];
    int idx0 = base + t * 4;
    int sum = 0;
#pragma unroll
    for (int j = 0; j < 4; j++) {
        int i = idx0 + j;
        v[j] = (i < N) ? counts[i] : 0;
        sum += v[j];
    }
    sdata[t] = sum;
    __syncthreads();
    for (int off = 1; off < 256; off <<= 1) {
        int x = (t >= off) ? sdata[t - off] : 0;
        __syncthreads();
        sdata[t] += x;
        __syncthreads();
    }
    int incl = sdata[t];
    int excl = incl - sum;
    if (t == 255) blocksums[b] = incl;
    int run = excl;
#pragma unroll
    for (int j = 0; j < 4; j++) {
        int i = idx0 + j;
        if (i < N) offsets[i] = run;
        run += v[j];
    }
}

__global__ __launch_bounds__(128) void scan_phase2(int* __restrict__ blocksums, int nb) {
    __shared__ int s[128];
    int t = threadIdx.x;
    int v = (t < nb) ? blocksums[t] : 0;
    s[t] = v;
    __syncthreads();
    for (int off = 1; off < 128; off <<= 1) {
        int x = (t >= off) ? s[t - off] : 0;
        __syncthreads();
        s[t] += x;
        __syncthreads();
    }
    if (t < nb) blocksums[t] = s[t] - v;   // exclusive
}

__global__ void scan_phase3(int* __restrict__ offsets, const int* __restrict__ blocksums,
                            int* __restrict__ cursor, int N, int total) {
    int i = blockIdx.x * blockDim.x + threadIdx.x;
    if (i < N) {
        int o = offsets[i] + blocksums[i >> 10];
        offsets[i] = o;
        cursor[i] = o;
    }
    if (i == N) offsets[N] = total;
}

__global__ void fill_kernel(const int* __restrict__ src, const int* __restrict__ dst,
                            int* __restrict__ cursor, int* __restrict__ col, int E, int N) {
    int i = blockIdx.x * blockDim.x + threadIdx.x;
    int tot = E + N;
    if (i >= tot) return;
    int s, d;
    if (i < E) { s = src[i]; d = dst[i]; }
    else       { s = d = i - E; }
    int p = atomicAdd(&cursor[d], 1);
    col[p] = s;
}

// ---------------- pull-SpMM: one wave per dst row -------------------------
__global__ __launch_bounds__(256) void spmm_kernel(
    const float* __restrict__ zin, const float* __restrict__ h0,
    const int* __restrict__ offs, const int* __restrict__ col,
    const float* __restrict__ dinv, float* __restrict__ zout, int N) {
    int gw = blockIdx.x * 4 + (threadIdx.x >> 6);
    if (gw >= N) return;
    int lane = threadIdx.x & 63;
    int beg = offs[gw], end = offs[gw + 1];
    float ax = 0.f, ay = 0.f, az = 0.f, aw = 0.f;
    float bx = 0.f, by = 0.f, bz = 0.f, bw = 0.f;
    int e = beg;
    for (; e + 1 < end; e += 2) {
        int s0 = col[e], s1 = col[e + 1];
        float w0 = dinv[s0], w1 = dinv[s1];
        float4 v0 = *(const float4*)(zin + (size_t)s0 * 256 + lane * 4);
        float4 v1 = *(const float4*)(zin + (size_t)s1 * 256 + lane * 4);
        ax += w0 * v0.x; ay += w0 * v0.y; az += w0 * v0.z; aw += w0 * v0.w;
        bx += w1 * v1.x; by += w1 * v1.y; bz += w1 * v1.z; bw += w1 * v1.w;
    }
    if (e < end) {
        int s0 = col[e];
        float w0 = dinv[s0];
        float4 v0 = *(const float4*)(zin + (size_t)s0 * 256 + lane * 4);
        ax += w0 * v0.x; ay += w0 * v0.y; az += w0 * v0.z; aw += w0 * v0.w;
    }
    float wd = BETA * dinv[gw];
    float4 h = *(const float4*)(h0 + (size_t)gw * 256 + lane * 4);
    float4 o;
    o.x = wd * (ax + bx) + ALPHA * h.x;
    o.y = wd * (ay + by) + ALPHA * h.y;
    o.z = wd * (az + bz) + ALPHA * h.z;
    o.w = wd * (aw + bw) + ALPHA * h.w;
    *(float4*)(zout + (size_t)gw * 256 + lane * 4) = o;
}

extern "C" void kernel_launch(void* const* d_in, const int* in_sizes, int n_in,
                              void* d_out, int out_size, void* d_ws, size_t ws_size,
                              hipStream_t stream) {
    const float* x  = (const float*)d_in[0];
    const int* ei   = (const int*)d_in[1];     // [2,E] int32 per harness convention
    const float* W1 = (const float*)d_in[2];
    const float* b1 = (const float*)d_in[3];
    float* out = (float*)d_out;

    const int N = in_sizes[0] / 512;           // 100000
    const int E = in_sizes[1] / 2;             // 3200000
    const int* src = ei;
    const int* dst = ei + E;
    const int NNZ = E + N;

    // workspace carve-up (~220 MB)
    char* w = (char*)d_ws;
    float* h0 = (float*)w;      w += (size_t)N * 256 * 4;
    float* zA = (float*)w;      w += (size_t)N * 256 * 4;
    float* Wt = (float*)w;      w += (size_t)512 * 256 * 4;
    float* dinv = (float*)w;    w += (size_t)N * 4;
    int* counts = (int*)w;      w += (size_t)N * 4;          // reused as cursor
    int* offsets = (int*)w;     w += (size_t)(N + 1) * 4;
    int* blocksums = (int*)w;   w += 128 * 4;
    int* col = (int*)w;         w += (size_t)NNZ * 4;

    // 1) transpose W1 -> Wt
    transpose_w<<<(512 * 256 + 255) / 256, 256, 0, stream>>>(W1, Wt);
    // 2) GEMM -> h0 (raw)
    dim3 ggrid((N + 63) / 64, 4);
    gemm_kernel<<<ggrid, 256, 0, stream>>>(x, Wt, b1, h0, N);
    // 3) normalize rows in place
    normalize_kernel<<<N, 256, 0, stream>>>(h0, N);
    // 4) degrees (incl self-loop)
    init_counts<<<(N + 255) / 256, 256, 0, stream>>>(counts, N);
    count_kernel<<<(E + 255) / 256, 256, 0, stream>>>(dst, counts, E);
    dinv_kernel<<<(N + 255) / 256, 256, 0, stream>>>(counts, dinv, N);
    // 5) scan -> offsets, cursor
    int nb = (N + 1023) / 1024;
    scan_phase1<<<nb, 256, 0, stream>>>(counts, offsets, blocksums, N);
    scan_phase2<<<1, 128, 0, stream>>>(blocksums, nb);
    scan_phase3<<<(N + 256) / 256, 256, 0, stream>>>(offsets, blocksums, counts, N, NNZ);
    // 6) fill CSR cols (counts buffer now = cursor)
    fill_kernel<<<(NNZ + 255) / 256, 256, 0, stream>>>(src, dst, counts, col, E, N);
    // 7) APPNP: 10 pull-SpMM steps; it even->zA, odd->out; it=9 lands in out
    const float* cur = h0;
    int nblk = (N + 3) / 4;
    for (int it = 0; it < 10; ++it) {
        float* nxt = (it & 1) ? out : zA;
        spmm_kernel<<<nblk, 256, 0, stream>>>(cur, h0, offsets, col, dinv, nxt, N);
        cur = nxt;
    }
}

// Round 2
// 3472.851 us; speedup vs baseline: 1.7265x; 1.7265x over previous
//
#include <hip/hip_runtime.h>
#include <hip/hip_fp16.h>

// Encoder: h = normalize_rows(x @ W1^T + b1) * 1.8 ; APPNP K=10, alpha=0.15
// N=100000, E=3200000, IN=512, OUT=256. Output fp32 [N,256].
//
// R1: propagation state in fp16 (y = dinv*z), halving the dominant gather
// traffic (3.38 GB -> 1.69 GB/iter) and removing the per-edge dinv load.
// Accumulation stays fp32; final iteration writes fp32 directly to d_out.

#define ALPHA 0.15f
#define BETA 0.85f
#define SCALE 1.8f

// ---------------- transpose W1 [256][512] -> Wt [512][256] ----------------
__global__ void transpose_w(const float* __restrict__ W1, float* __restrict__ Wt) {
    int i = blockIdx.x * blockDim.x + threadIdx.x;   // 512*256
    if (i >= 512 * 256) return;
    int k = i >> 8;          // 0..511
    int n = i & 255;         // 0..255
    Wt[i] = W1[n * 512 + k];
}

// ---------------- fp32 GEMM: C[M,256] = A[M,512] * B[512,256] + bias ------
__global__ __launch_bounds__(256) void gemm_kernel(
    const float* __restrict__ A, const float* __restrict__ B,
    const float* __restrict__ bias, float* __restrict__ C, int M) {
    __shared__ float As[16][65];   // [k][m], padded
    __shared__ float Bs[16][64];   // [k][n]
    const int tid = threadIdx.x;
    const int tx = tid & 15;       // n-dim
    const int ty = tid >> 4;       // m-dim
    const int m0 = blockIdx.x * 64;
    const int n0 = blockIdx.y * 64;

    float acc[4][4];
#pragma unroll
    for (int i = 0; i < 4; i++)
#pragma unroll
        for (int j = 0; j < 4; j++) acc[i][j] = 0.0f;

    const int arow = tid >> 2;          // 0..63
    const int akseg = tid & 3;          // 0..3 (4 k-floats each)
    const int bkk = tid >> 4;           // 0..15
    const int bnseg = tid & 15;         // 0..15

    for (int k0 = 0; k0 < 512; k0 += 16) {
        float4 av = make_float4(0.f, 0.f, 0.f, 0.f);
        if (m0 + arow < M)
            av = *(const float4*)(A + (size_t)(m0 + arow) * 512 + k0 + akseg * 4);
        As[akseg * 4 + 0][arow] = av.x;
        As[akseg * 4 + 1][arow] = av.y;
        As[akseg * 4 + 2][arow] = av.z;
        As[akseg * 4 + 3][arow] = av.w;
        float4 bv = *(const float4*)(B + (size_t)(k0 + bkk) * 256 + n0 + bnseg * 4);
        *(float4*)(&Bs[bkk][bnseg * 4]) = bv;
        __syncthreads();

#pragma unroll
        for (int kk = 0; kk < 16; kk++) {
            float a[4], b[4];
#pragma unroll
            for (int i = 0; i < 4; i++) a[i] = As[kk][ty * 4 + i];
#pragma unroll
            for (int j = 0; j < 4; j++) b[j] = Bs[kk][tx * 4 + j];
#pragma unroll
            for (int i = 0; i < 4; i++)
#pragma unroll
                for (int j = 0; j < 4; j++) acc[i][j] += a[i] * b[j];
        }
        __syncthreads();
    }

    float4 bias4 = *(const float4*)(bias + n0 + tx * 4);
#pragma unroll
    for (int i = 0; i < 4; i++) {
        int m = m0 + ty * 4 + i;
        if (m < M) {
            float4 o;
            o.x = acc[i][0] + bias4.x;
            o.y = acc[i][1] + bias4.y;
            o.z = acc[i][2] + bias4.z;
            o.w = acc[i][3] + bias4.w;
            *(float4*)(C + (size_t)m * 256 + n0 + tx * 4) = o;
        }
    }
}

// ------ row L2-normalize * 1.8; emit fp16 h16 (alpha term) + y0 = h*dinv --
__global__ __launch_bounds__(256) void normalize_kernel(
    const float* __restrict__ h, const float* __restrict__ dinv,
    __half* __restrict__ h16, __half* __restrict__ y0, int N) {
    int n = blockIdx.x;
    if (n >= N) return;
    int t = threadIdx.x;
    float v = h[(size_t)n * 256 + t];
    float ss = v * v;
#pragma unroll
    for (int off = 32; off > 0; off >>= 1) ss += __shfl_down(ss, off, 64);
    __shared__ float wsum[4];
    int w = t >> 6, lane = t & 63;
    if (lane == 0) wsum[w] = ss;
    __syncthreads();
    float tot = wsum[0] + wsum[1] + wsum[2] + wsum[3];
    float nrm = sqrtf(tot);
    float s = SCALE / fmaxf(nrm, 1e-12f);
    float hv = v * s;
    h16[(size_t)n * 256 + t] = __float2half(hv);
    y0[(size_t)n * 256 + t] = __float2half(hv * dinv[n]);
}

// ---------------- degree / CSR build --------------------------------------
__global__ void init_counts(int* __restrict__ counts, int N) {
    int i = blockIdx.x * blockDim.x + threadIdx.x;
    if (i < N) counts[i] = 1;   // self-loop
}

__global__ void count_kernel(const int* __restrict__ dst, int* __restrict__ counts, int E) {
    int i = blockIdx.x * blockDim.x + threadIdx.x;
    if (i < E) atomicAdd(&counts[dst[i]], 1);
}

__global__ void dinv_kernel(const int* __restrict__ counts, float* __restrict__ dinv, int N) {
    int i = blockIdx.x * blockDim.x + threadIdx.x;
    if (i < N) dinv[i] = rsqrtf((float)counts[i]);
}

__global__ __launch_bounds__(256) void scan_phase1(
    const int* __restrict__ counts, int* __restrict__ offsets,
    int* __restrict__ blocksums, int N) {
    __shared__ int sdata[256];
    int b = blockIdx.x;
    int base = b * 1024;
    int t = threadIdx.x;
    int v[4];
    int idx0 = base + t * 4;
    int sum = 0;
#pragma unroll
    for (int j = 0; j < 4; j++) {
        int i = idx0 + j;
        v[j] = (i < N) ? counts[i] : 0;
        sum += v[j];
    }
    sdata[t] = sum;
    __syncthreads();
    for (int off = 1; off < 256; off <<= 1) {
        int x = (t >= off) ? sdata[t - off] : 0;
        __syncthreads();
        sdata[t] += x;
        __syncthreads();
    }
    int incl = sdata[t];
    int excl = incl - sum;
    if (t == 255) blocksums[b] = incl;
    int run = excl;
#pragma unroll
    for (int j = 0; j < 4; j++) {
        int i = idx0 + j;
        if (i < N) offsets[i] = run;
        run += v[j];
    }
}

__global__ __launch_bounds__(128) void scan_phase2(int* __restrict__ blocksums, int nb) {
    __shared__ int s[128];
    int t = threadIdx.x;
    int v = (t < nb) ? blocksums[t] : 0;
    s[t] = v;
    __syncthreads();
    for (int off = 1; off < 128; off <<= 1) {
        int x = (t >= off) ? s[t - off] : 0;
        __syncthreads();
        s[t] += x;
        __syncthreads();
    }
    if (t < nb) blocksums[t] = s[t] - v;   // exclusive
}

__global__ void scan_phase3(int* __restrict__ offsets, const int* __restrict__ blocksums,
                            int* __restrict__ cursor, int N, int total) {
    int i = blockIdx.x * blockDim.x + threadIdx.x;
    if (i < N) {
        int o = offsets[i] + blocksums[i >> 10];
        offsets[i] = o;
        cursor[i] = o;
    }
    if (i == N) offsets[N] = total;
}

__global__ void fill_kernel(const int* __restrict__ src, const int* __restrict__ dst,
                            int* __restrict__ cursor, int* __restrict__ col, int E, int N) {
    int i = blockIdx.x * blockDim.x + threadIdx.x;
    int tot = E + N;
    if (i >= tot) return;
    int s, d;
    if (i < E) { s = src[i]; d = dst[i]; }
    else       { s = d = i - E; }
    int p = atomicAdd(&cursor[d], 1);
    col[p] = s;
}

// ---------------- pull-SpMM over fp16 state: one wave per dst row ---------
__device__ __forceinline__ void acc_half4(float4& a, float2 r) {
    union { float2 f; __half2 h[2]; } u;
    u.f = r;
    float2 lo = __half22float2(u.h[0]);
    float2 hi = __half22float2(u.h[1]);
    a.x += lo.x; a.y += lo.y; a.z += hi.x; a.w += hi.y;
}

template <bool FINAL>
__global__ __launch_bounds__(256) void spmm_kernel(
    const __half* __restrict__ yin, const __half* __restrict__ h16,
    const int* __restrict__ offs, const int* __restrict__ col,
    const float* __restrict__ dinv, void* __restrict__ outp, int N) {
    int gw = blockIdx.x * 4 + (threadIdx.x >> 6);
    if (gw >= N) return;
    int lane = threadIdx.x & 63;
    int beg = offs[gw], end = offs[gw + 1];

    float4 a0 = make_float4(0.f, 0.f, 0.f, 0.f);
    float4 a1 = make_float4(0.f, 0.f, 0.f, 0.f);
    float4 a2 = make_float4(0.f, 0.f, 0.f, 0.f);
    float4 a3 = make_float4(0.f, 0.f, 0.f, 0.f);

    int e = beg;
    for (; e + 3 < end; e += 4) {
        int s0 = __builtin_nontemporal_load(col + e);
        int s1 = __builtin_nontemporal_load(col + e + 1);
        int s2 = __builtin_nontemporal_load(col + e + 2);
        int s3 = __builtin_nontemporal_load(col + e + 3);
        float2 r0 = ((const float2*)(yin + (size_t)s0 * 256))[lane];
        float2 r1 = ((const float2*)(yin + (size_t)s1 * 256))[lane];
        float2 r2 = ((const float2*)(yin + (size_t)s2 * 256))[lane];
        float2 r3 = ((const float2*)(yin + (size_t)s3 * 256))[lane];
        acc_half4(a0, r0); acc_half4(a1, r1); acc_half4(a2, r2); acc_half4(a3, r3);
    }
    for (; e < end; ++e) {
        int s0 = __builtin_nontemporal_load(col + e);
        float2 r0 = ((const float2*)(yin + (size_t)s0 * 256))[lane];
        acc_half4(a0, r0);
    }

    float dg = dinv[gw];
    float wd = BETA * dg;

    // alpha * h0 term (fp16, streaming)
    const float* hp = (const float*)(h16 + (size_t)gw * 256) + lane * 2;
    float hx = __builtin_nontemporal_load(hp);
    float hy = __builtin_nontemporal_load(hp + 1);
    float4 hh;
    {
        union { float f; __half2 h; } ux, uy;
        ux.f = hx; uy.f = hy;
        float2 lo = __half22float2(ux.h);
        float2 hi = __half22float2(uy.h);
        hh.x = lo.x; hh.y = lo.y; hh.z = hi.x; hh.w = hi.y;
    }

    float4 o;
    o.x = wd * (a0.x + a1.x + a2.x + a3.x) + ALPHA * hh.x;
    o.y = wd * (a0.y + a1.y + a2.y + a3.y) + ALPHA * hh.y;
    o.z = wd * (a0.z + a1.z + a2.z + a3.z) + ALPHA * hh.z;
    o.w = wd * (a0.w + a1.w + a2.w + a3.w) + ALPHA * hh.w;

    if (FINAL) {
        float* op = (float*)outp + (size_t)gw * 256 + lane * 4;
        __builtin_nontemporal_store(o.x, op);
        __builtin_nontemporal_store(o.y, op + 1);
        __builtin_nontemporal_store(o.z, op + 2);
        __builtin_nontemporal_store(o.w, op + 3);
    } else {
        // store y = dinv[d] * z for the next iteration's gathers
        __half2 p0 = __floats2half2_rn(o.x * dg, o.y * dg);
        __half2 p1 = __floats2half2_rn(o.z * dg, o.w * dg);
        union { float f; __half2 h; } u0, u1;
        u0.h = p0; u1.h = p1;
        float* op = (float*)((__half*)outp + (size_t)gw * 256) + lane * 2;
        __builtin_nontemporal_store(u0.f, op);
        __builtin_nontemporal_store(u1.f, op + 1);
    }
}

extern "C" void kernel_launch(void* const* d_in, const int* in_sizes, int n_in,
                              void* d_out, int out_size, void* d_ws, size_t ws_size,
                              hipStream_t stream) {
    const float* x  = (const float*)d_in[0];
    const int* ei   = (const int*)d_in[1];
    const float* W1 = (const float*)d_in[2];
    const float* b1 = (const float*)d_in[3];
    float* out = (float*)d_out;

    const int N = in_sizes[0] / 512;           // 100000
    const int E = in_sizes[1] / 2;             // 3200000
    const int* src = ei;
    const int* dst = ei + E;
    const int NNZ = E + N;

    // workspace carve-up (~270 MB); h0 (fp32) region is reused as yA (fp16)
    char* w = (char*)d_ws;
    float* h0 = (float*)w;      w += (size_t)N * 256 * 4;      // fp32 GEMM out / later yA
    __half* h16 = (__half*)w;   w += (size_t)N * 256 * 2;      // alpha term
    __half* y0 = (__half*)w;    w += (size_t)N * 256 * 2;      // initial state
    __half* yB = (__half*)w;    w += (size_t)N * 256 * 2;      // ping-pong B
    float* Wt = (float*)w;      w += (size_t)512 * 256 * 4;
    float* dinv = (float*)w;    w += (size_t)N * 4;
    int* counts = (int*)w;      w += (size_t)N * 4;            // reused as cursor
    int* offsets = (int*)w;     w += (size_t)(N + 64) * 4;
    int* blocksums = (int*)w;   w += 128 * 4;
    int* col = (int*)w;         w += (size_t)NNZ * 4;
    __half* yA = (__half*)h0;

    // degrees (incl self-loop) + dinv — needed by normalize
    init_counts<<<(N + 255) / 256, 256, 0, stream>>>(counts, N);
    count_kernel<<<(E + 255) / 256, 256, 0, stream>>>(dst, counts, E);
    dinv_kernel<<<(N + 255) / 256, 256, 0, stream>>>(counts, dinv, N);
    // linear1
    transpose_w<<<(512 * 256 + 255) / 256, 256, 0, stream>>>(W1, Wt);
    dim3 ggrid((N + 63) / 64, 4);
    gemm_kernel<<<ggrid, 256, 0, stream>>>(x, Wt, b1, h0, N);
    // normalize -> h16, y0 (h0 fp32 dead after this; region becomes yA)
    normalize_kernel<<<N, 256, 0, stream>>>(h0, dinv, h16, y0, N);
    // CSR
    int nb = (N + 1023) / 1024;
    scan_phase1<<<nb, 256, 0, stream>>>(counts, offsets, blocksums, N);
    scan_phase2<<<1, 128, 0, stream>>>(blocksums, nb);
    scan_phase3<<<(N + 256) / 256, 256, 0, stream>>>(offsets, blocksums, counts, N, NNZ);
    fill_kernel<<<(NNZ + 255) / 256, 256, 0, stream>>>(src, dst, counts, col, E, N);
    // APPNP: 9 fp16->fp16 steps + final fp16->fp32 into d_out
    int nblk = (N + 3) / 4;
    const __half* cur = y0;
    for (int it = 0; it < 9; ++it) {
        __half* nxt = (it & 1) ? yB : yA;
        spmm_kernel<false><<<nblk, 256, 0, stream>>>(cur, h16, offsets, col, dinv,
                                                     (void*)nxt, N);
        cur = nxt;
    }
    spmm_kernel<true><<<nblk, 256, 0, stream>>>(cur, h16, offsets, col, dinv,
                                                (void*)out, N);
}